// Round 9
// baseline (62.251 us; speedup 1.0000x reference)
//
#include <hip/hip_runtime.h>
#include <cmath>

// Sampler: temperature(0.7) -> top-p(0.9, HF semantics) -> top-k(50)
// -> softmax -> inverse-CDF multinomial with given uniform u.
//
// R9: single full read. zmc_kernel loads each 4096-float segment entirely
// into registers (16/thread), block-reduces the segment max, then computes
// the Z partial (exp2, per-seg anchor; finish rescales by expf((ms-M)/T) --
// the R2-R7-validated pattern) and collects candidates (l > ms-5, a superset
// of the validated global window l > M-5) all from registers. 2 kernels,
// 1 full pass, vs R8's 3 kernels / 2 full passes.

constexpr int   NSPLIT = 32;             // segments/row
constexpr int   BLK    = 256;
constexpr int   TILE4  = BLK * 4;        // float4s per register tile (4096 floats)
constexpr int   NBINS  = 1024;
constexpr int   BPL    = NBINS / 64;
constexpr int   TOPK   = 50;
constexpr float TEMP   = 0.7f;
constexpr float SPANS  = 5.0f;           // collect window below seg max
constexpr float SPANC  = 5.0f;           // finish hist window below global max
constexpr int   CAPSEG = 512;            // slots per (row,seg)
constexpr int   NCAND  = NSPLIT * CAPSEG;
constexpr int   BLK_F  = 256;
constexpr int   CAPC   = 128;            // compacted survivors cap
// exp((l-M)/T) == exp2((l-M) * LOG2E_OVER_T)
constexpr float LOG2E_OVER_T = (float)(1.4426950408889634 / 0.7);

__global__ __launch_bounds__(BLK)
void zmc_kernel(const float* __restrict__ logits,
                float* __restrict__ segmax, float* __restrict__ segz,
                float* __restrict__ cand_v, int* __restrict__ cand_i,
                unsigned int* __restrict__ cnt16,
                int V, int seglen)
{
  const int seg  = blockIdx.x;
  const int row  = blockIdx.y;
  const int tid  = threadIdx.x, lane = tid & 63, wave = tid >> 6;
  const int start = seg * seglen;
  const int len  = (V - start < seglen) ? (V - start) : seglen;

  __shared__ float red[BLK / 64];
  __shared__ float s_bm;
  __shared__ unsigned int s_nf;
  __shared__ float bl_v[CAPSEG];
  __shared__ int   bl_i[CAPSEG];

  if (len <= 0) {
    if (tid == 0) { segmax[row * NSPLIT + seg] = -INFINITY;
                    segz  [row * NSPLIT + seg] = 0.f;
                    cnt16 [row * NSPLIT + seg] = 0u; }
    return;
  }
  if (tid == 0) s_nf = 0u;
  __syncthreads();

  const float* __restrict__ base = logits + (size_t)row * V + start;
  const int len4 = len >> 2;
  const int tail = len & 3;
  const float4* b4 = reinterpret_cast<const float4*>(base);

  float mb = -INFINITY;       // block running max (uniform after each tile)
  float zs = 0.f;             // per-thread Z partial, anchored at current mb
  const int ntiles = (len4 + TILE4 - 1) / TILE4;

  for (int t = 0; t < ntiles; ++t) {
    const int tb = t * TILE4;
    float4 r[4];
    #pragma unroll
    for (int u = 0; u < 4; ++u) {
      int i4 = tb + u * BLK + tid;
      r[u] = (i4 < len4) ? b4[i4]
                         : make_float4(-INFINITY, -INFINITY, -INFINITY, -INFINITY);
    }
    // tile max -> block max
    float tm = -INFINITY;
    #pragma unroll
    for (int u = 0; u < 4; ++u)
      tm = fmaxf(tm, fmaxf(fmaxf(r[u].x, r[u].y), fmaxf(r[u].z, r[u].w)));
    #pragma unroll
    for (int off = 32; off >= 1; off >>= 1) tm = fmaxf(tm, __shfl_xor(tm, off, 64));
    if (lane == 0) red[wave] = tm;
    __syncthreads();
    if (tid == 0) {
      float v = red[0];
      for (int w = 1; w < BLK / 64; ++w) v = fmaxf(v, red[w]);
      s_bm = v;
    }
    __syncthreads();
    const float mnew = fmaxf(mb, s_bm);
    if (mnew > mb) zs *= exp2f((mb - mnew) * LOG2E_OVER_T);  // first tile: 0*0=0
    mb = mnew;
    const float lo = mb - SPANS;

    // Z + collect from registers (invalid lanes hold -inf -> contribute 0)
    #pragma unroll
    for (int u = 0; u < 4; ++u) {
      const int i4 = tb + u * BLK + tid;
      #pragma unroll
      for (int c = 0; c < 4; ++c) {
        float l = (c == 0) ? r[u].x : (c == 1) ? r[u].y : (c == 2) ? r[u].z : r[u].w;
        zs += exp2f((l - mb) * LOG2E_OVER_T);
        if (l > lo) {
          unsigned int p = atomicAdd(&s_nf, 1u);
          if (p < CAPSEG) { bl_v[p] = l; bl_i[p] = start + (i4 << 2) + c; }
        }
      }
    }
    __syncthreads();   // protect s_bm for next tile
  }

  // scalar tail (<4 elements)
  if (tail) {
    const int idx = (len4 << 2) + tid;
    float l = (idx < len) ? base[idx] : -INFINITY;
    float tm = l;
    #pragma unroll
    for (int off = 32; off >= 1; off >>= 1) tm = fmaxf(tm, __shfl_xor(tm, off, 64));
    if (lane == 0) red[wave] = tm;
    __syncthreads();
    if (tid == 0) {
      float v = red[0];
      for (int w = 1; w < BLK / 64; ++w) v = fmaxf(v, red[w]);
      s_bm = v;
    }
    __syncthreads();
    const float mnew = fmaxf(mb, s_bm);
    if (mnew > mb) zs *= exp2f((mb - mnew) * LOG2E_OVER_T);
    mb = mnew;
    zs += exp2f((l - mb) * LOG2E_OVER_T);
    if (l > mb - SPANS) {
      unsigned int p = atomicAdd(&s_nf, 1u);
      if (p < CAPSEG) { bl_v[p] = l; bl_i[p] = start + idx; }
    }
    __syncthreads();
  }

  // reduce Z partial, write outputs
  #pragma unroll
  for (int off = 32; off >= 1; off >>= 1) zs += __shfl_xor(zs, off, 64);
  if (lane == 0) red[wave] = zs;
  __syncthreads();
  if (tid == 0) {
    float v = red[0];
    for (int w = 1; w < BLK / 64; ++w) v += red[w];
    segz  [row * NSPLIT + seg] = v;      // anchored at seg max mb
    segmax[row * NSPLIT + seg] = mb;
  }
  unsigned int nf = s_nf; if (nf > CAPSEG) nf = CAPSEG;
  float* cvout = cand_v + ((size_t)row * NSPLIT + seg) * CAPSEG;
  int*   ciout = cand_i + ((size_t)row * NSPLIT + seg) * CAPSEG;
  for (unsigned int i = tid; i < nf; i += BLK) { cvout[i] = bl_v[i]; ciout[i] = bl_i[i]; }
  if (tid == 0) cnt16[row * NSPLIT + seg] = nf;
}

__global__ __launch_bounds__(BLK_F)
void finish_kernel(const float* __restrict__ segmax, const float* __restrict__ segz,
                   const float* __restrict__ cand_v, const int* __restrict__ cand_i,
                   const unsigned int* __restrict__ cnt16,
                   const float* __restrict__ uvec, int* __restrict__ out)
{
  const int row  = blockIdx.x;
  const int tid  = threadIdx.x;
  const int lane = tid & 63;
  const float invT = 1.0f / TEMP;

  __shared__ unsigned int hist[NBINS];
  __shared__ unsigned int chunk[64];
  __shared__ unsigned int cnt_s[NSPLIT];
  __shared__ float s_M, s_Z;
  __shared__ int   s_bstar;
  __shared__ unsigned int s_nc;
  __shared__ float fv[CAPC];
  __shared__ int   fi[CAPC];
  __shared__ float ov_[CAPC];     // rank-ordered values
  __shared__ int   oi_[CAPC];     // rank-ordered indices
  __shared__ float eo[64];        // e per rank
  __shared__ float o2e[64];       // index-sorted kept e
  __shared__ int   o2i[64];
  __shared__ int   s_nk;

  if (tid < NSPLIT) cnt_s[tid] = cnt16[row * NSPLIT + tid];
  if (tid < 64) {
    float sm = (lane < NSPLIT) ? segmax[row * NSPLIT + lane] : -INFINITY;
    float m = sm;
    #pragma unroll
    for (int off = 32; off >= 1; off >>= 1) m = fmaxf(m, __shfl_xor(m, off, 64));
    // rescale per-seg-anchored Z partials to the global max (R2-R7 pattern)
    float zt = (lane < NSPLIT) ? segz[row * NSPLIT + lane] * expf((sm - m) * invT) : 0.f;
    #pragma unroll
    for (int off = 32; off >= 1; off >>= 1) zt += __shfl_xor(zt, off, 64);
    if (lane == 0) { s_M = m; s_Z = zt; s_nc = 0u; }
  }
  for (int i = tid; i < NBINS; i += BLK_F) hist[i] = 0u;
  __syncthreads();

  const float M  = s_M;
  const float lo = M - SPANC;
  const float binscale = (float)NBINS / SPANC;
  const float* cvrow = cand_v + (size_t)row * NCAND;
  const int*   cirow = cand_i + (size_t)row * NCAND;

  // histogram of candidates (below-window values clamp to bin 0)
  for (int i = tid; i < NCAND; i += BLK_F) {
    int sg = i >> 9;               // CAPSEG = 512
    int ix = i & (CAPSEG - 1);
    if ((unsigned)ix < cnt_s[sg]) {
      float v = cvrow[i];
      int b = (int)((v - lo) * binscale);
      b = (b < 0) ? 0 : ((b > NBINS - 1) ? (NBINS - 1) : b);
      atomicAdd(&hist[b], 1u);
    }
  }
  __syncthreads();

  if (tid < 64) {
    unsigned int csum = 0;
    const int cb = tid * BPL;
    #pragma unroll
    for (int j = 0; j < BPL; ++j) csum += hist[cb + j];
    chunk[tid] = csum;
  }
  __syncthreads();
  if (tid < 64) {
    unsigned int csum = chunk[tid];
    unsigned int suf = 0;
    for (int l2 = 0; l2 < 64; ++l2) {
      unsigned int c2 = chunk[l2];
      suf += (l2 >= tid) ? c2 : 0u;
    }
    unsigned long long bal = __ballot(suf >= (unsigned)TOPK);
    if (bal == 0ull) {
      if (tid == 0) s_bstar = 0;
    } else {
      int L = 63 - __builtin_clzll(bal);
      if (tid == L) {
        unsigned int running = suf - csum;
        const int cb = tid * BPL;
        unsigned int h[BPL];
        #pragma unroll
        for (int j = 0; j < BPL; ++j) h[j] = hist[cb + j];
        int bsel = cb;
        #pragma unroll
        for (int j = BPL - 1; j >= 0; --j) {
          running += h[j];
          if (running >= (unsigned)TOPK) { bsel = cb + j; break; }
        }
        s_bstar = bsel;
      }
    }
  }
  __syncthreads();

  // compact survivors (bin >= bstar)
  const int bstar = s_bstar;
  for (int i = tid; i < NCAND; i += BLK_F) {
    int sg = i >> 9;
    int ix = i & (CAPSEG - 1);
    if ((unsigned)ix < cnt_s[sg]) {
      float v = cvrow[i];
      int b = (int)((v - lo) * binscale);
      b = (b < 0) ? 0 : ((b > NBINS - 1) ? (NBINS - 1) : b);
      if (b >= bstar) {
        unsigned int p = atomicAdd(&s_nc, 1u);
        if (p < CAPC) { fv[p] = v; fi[p] = cirow[i]; }
      }
    }
  }
  __syncthreads();

  // all-pairs descending rank (value desc, index asc) + scatter
  const int ns = ((int)s_nc < CAPC) ? (int)s_nc : CAPC;
  if (tid < 64) {
    float c0v = (lane < ns)      ? fv[lane]      : 0.f;
    int   c0i = (lane < ns)      ? fi[lane]      : 0;
    float c1v = (lane + 64 < ns) ? fv[lane + 64] : 0.f;
    int   c1i = (lane + 64 < ns) ? fi[lane + 64] : 0;
    int r0 = 0, r1 = 0;
    for (int j = 0; j < ns; ++j) {
      float vj = fv[j]; int ij = fi[j];
      if (vj > c0v || (vj == c0v && ij < c0i)) ++r0;
      if (vj > c1v || (vj == c1v && ij < c1i)) ++r1;
    }
    if (lane < ns)      { ov_[r0] = c0v; oi_[r0] = c0i; }
    if (lane + 64 < ns) { ov_[r1] = c1v; oi_[r1] = c1i; }
  }
  __syncthreads();

  // per-rank exp on the exact reference path
  const float Mx = M / TEMP;                 // fl(M/0.7)
  if (tid < 64 && lane < ns && lane < TOPK) {
    float x = ov_[lane] / TEMP;              // fl(v/0.7) per element
    eo[lane] = expf(x - Mx);
  }
  __syncthreads();

  // sequential fp32 nucleus scan (lane 0)
  if (tid == 0) {
    const float thresh = 0.9f * s_Z;
    const int nkmax = (ns < TOPK) ? ns : TOPK;
    float cum = 0.f; int nk = 0;
    for (int k = 0; k < TOPK; ++k) {
      float ek = eo[k];
      bool take = (k < nkmax) && (cum < thresh);
      if (take) { cum += ek; nk++; }
    }
    s_nk = nk;
  }
  __syncthreads();

  // rank kept tokens by original index
  const int nk = s_nk;
  if (tid < 64 && lane < nk) {
    int myi = oi_[lane];
    int rank = 0;
    for (int j = 0; j < nk; ++j) rank += (oi_[j] < myi) ? 1 : 0;
    o2e[rank] = eo[lane]; o2i[rank] = myi;
  }
  __syncthreads();

  // sequential CDF sample (lane 0)
  if (tid == 0) {
    float S = 0.f;
    for (int j = 0; j < nk; ++j) S += o2e[j];
    const float uu = uvec[row];
    float c = 0.f; int token = 0; int found = 0;
    for (int j = 0; j < nk; ++j) {
      float q = o2e[j] / S;                  // mirrors softmax per-element divide
      c += q;
      if (!found && c >= uu) { token = o2i[j]; found = 1; }
    }
    out[row] = token;
  }
}

extern "C" void kernel_launch(void* const* d_in, const int* in_sizes, int n_in,
                              void* d_out, int out_size, void* d_ws, size_t ws_size,
                              hipStream_t stream) {
  const float* logits = (const float*)d_in[0];
  // d_in[1] = input_ids (unused: repetition_penalty == 1.0)
  const float* u = (const float*)d_in[2];
  int* out = (int*)d_out;
  const int B = in_sizes[2];
  const int V = in_sizes[0] / B;
  int seglen = (V + NSPLIT - 1) / NSPLIT;
  seglen = (seglen + 3) & ~3;

  // workspace layout (4-byte aligned):
  char* ws = (char*)d_ws;
  float* segmax = (float*)ws;                                   // B*NSPLIT
  float* segz   = segmax + (size_t)B * NSPLIT;                  // B*NSPLIT
  unsigned int* cnt16 = (unsigned int*)(segz + (size_t)B * NSPLIT); // B*NSPLIT
  float* cand_v = (float*)(cnt16 + (size_t)B * NSPLIT);         // B*NCAND
  int*   cand_i = (int*)(cand_v + (size_t)B * NCAND);           // B*NCAND

  zmc_kernel<<<dim3(NSPLIT, B), dim3(BLK), 0, stream>>>(
      logits, segmax, segz, cand_v, cand_i, cnt16, V, seglen);
  finish_kernel<<<dim3(B), dim3(BLK_F), 0, stream>>>(
      segmax, segz, cand_v, cand_i, cnt16, u, out);
}

// Round 10
// 48.975 us; speedup vs baseline: 1.2711x; 1.2711x over previous
//
#include <hip/hip_runtime.h>
#include <cmath>

// Sampler: temperature(0.7) -> top-p(0.9, HF semantics) -> top-k(50)
// -> softmax -> inverse-CDF multinomial with given uniform u.
//
// R10: revert to R8's 3-kernel structure (R9's fused zmc over-collected via
// per-seg windows and finish's 2x16384-slot scan was 43us of serial latency).
// finish redesigned: prefix-sum of per-seg counts -> dense gather of the
// ~730 real candidates into LDS -> all passes run over n, not NCAND slots.
// zcol: candidates stored straight to global slots (no LDS staging).

constexpr int   NSEGA  = 64;             // kernel A segments/row
constexpr int   NSPLIT = 32;             // kernel B segments/row
constexpr int   BLK    = 256;
constexpr int   NBINS  = 1024;
constexpr int   BPL    = NBINS / 64;
constexpr int   TOPK   = 50;
constexpr float TEMP   = 0.7f;
constexpr float SPANC  = 5.0f;           // collect/hist window below global max
constexpr int   CAPSEG = 128;            // slots per (row,seg)
constexpr int   NCAND  = NSPLIT * CAPSEG;
constexpr int   BLK_F  = 256;
constexpr int   NDENSE = 2048;           // dense candidate cap (LDS)
constexpr int   CAPC   = 128;            // compacted survivors cap
// exp((l-M)/T) == exp2((l-M) * LOG2E_OVER_T)
constexpr float LOG2E_OVER_T = (float)(1.4426950408889634 / 0.7);

__global__ __launch_bounds__(BLK)
void max_kernel(const float* __restrict__ logits, float* __restrict__ segmax,
                int V, int seglen)
{
  const int seg  = blockIdx.x;
  const int row  = blockIdx.y;
  const int tid  = threadIdx.x, lane = tid & 63, wave = tid >> 6;
  const int start = seg * seglen;
  const int len  = (V - start < seglen) ? (V - start) : seglen;

  __shared__ float red[BLK / 64];

  if (len <= 0) { if (tid == 0) segmax[row * NSEGA + seg] = -INFINITY; return; }

  const float* __restrict__ base = logits + (size_t)row * V + start;
  const bool vec4 = ((len & 3) == 0) && ((((size_t)base) & 15) == 0);
  const int len4 = vec4 ? (len >> 2) : 0;
  const float4* b4 = reinterpret_cast<const float4*>(base);

  float m = -INFINITY;
  {
    int i = tid;
    for (; i + BLK < len4; i += 2 * BLK) {       // 2x unroll for load ILP
      float4 a = b4[i];
      float4 b = b4[i + BLK];
      m = fmaxf(m, fmaxf(fmaxf(a.x, a.y), fmaxf(a.z, a.w)));
      m = fmaxf(m, fmaxf(fmaxf(b.x, b.y), fmaxf(b.z, b.w)));
    }
    for (; i < len4; i += BLK) {
      float4 a = b4[i];
      m = fmaxf(m, fmaxf(fmaxf(a.x, a.y), fmaxf(a.z, a.w)));
    }
  }
  for (int i = (len4 << 2) + tid; i < len; i += BLK) m = fmaxf(m, base[i]);
  #pragma unroll
  for (int off = 32; off >= 1; off >>= 1) m = fmaxf(m, __shfl_xor(m, off, 64));
  if (lane == 0) red[wave] = m;
  __syncthreads();
  if (tid == 0) {
    float v = red[0];
    for (int w = 1; w < BLK / 64; ++w) v = fmaxf(v, red[w]);
    segmax[row * NSEGA + seg] = v;
  }
}

__global__ __launch_bounds__(BLK)
void zcol_kernel(const float* __restrict__ logits, const float* __restrict__ segmax,
                 float* __restrict__ segz,
                 float* __restrict__ cand_v, int* __restrict__ cand_i,
                 unsigned int* __restrict__ cnt16,
                 int V, int seglen)
{
  const int seg  = blockIdx.x;
  const int row  = blockIdx.y;
  const int tid  = threadIdx.x, lane = tid & 63, wave = tid >> 6;
  const int start = seg * seglen;
  const int len  = (V - start < seglen) ? (V - start) : seglen;

  __shared__ float red[BLK / 64];
  __shared__ unsigned int s_nf;

  if (len <= 0) {
    if (tid == 0) { segz[row * NSPLIT + seg] = 0.f;
                    cnt16[row * NSPLIT + seg] = 0u; }
    return;
  }

  // global row max: 64 lanes read 64 A-segment maxes (L2-hot), reduce.
  float sm = segmax[row * NSEGA + lane];    // NSEGA == 64 == wave width
  #pragma unroll
  for (int off = 32; off >= 1; off >>= 1) sm = fmaxf(sm, __shfl_xor(sm, off, 64));
  const float M  = sm;
  const float lo = M - SPANC;

  if (tid == 0) s_nf = 0u;
  __syncthreads();                                  // b1: s_nf ready

  float* cvout = cand_v + ((size_t)row * NSPLIT + seg) * CAPSEG;
  int*   ciout = cand_i + ((size_t)row * NSPLIT + seg) * CAPSEG;

  const float* __restrict__ base = logits + (size_t)row * V + start;
  const bool vec4 = ((len & 3) == 0) && ((((size_t)base) & 15) == 0);
  const int len4 = vec4 ? (len >> 2) : 0;
  const float4* b4 = reinterpret_cast<const float4*>(base);

  float zs = 0.f;
  {
    int i = tid;
    for (; i + BLK < len4; i += 2 * BLK) {          // 2x unroll
      float4 a = b4[i];
      float4 b = b4[i + BLK];
      #pragma unroll
      for (int c = 0; c < 4; ++c) {
        float l = (c == 0) ? a.x : (c == 1) ? a.y : (c == 2) ? a.z : a.w;
        zs += exp2f((l - M) * LOG2E_OVER_T);
        if (l > lo) {
          unsigned int p = atomicAdd(&s_nf, 1u);
          if (p < CAPSEG) { cvout[p] = l; ciout[p] = start + (i << 2) + c; }
        }
      }
      #pragma unroll
      for (int c = 0; c < 4; ++c) {
        float l = (c == 0) ? b.x : (c == 1) ? b.y : (c == 2) ? b.z : b.w;
        zs += exp2f((l - M) * LOG2E_OVER_T);
        if (l > lo) {
          unsigned int p = atomicAdd(&s_nf, 1u);
          if (p < CAPSEG) { cvout[p] = l; ciout[p] = start + ((i + BLK) << 2) + c; }
        }
      }
    }
    for (; i < len4; i += BLK) {
      float4 a = b4[i];
      #pragma unroll
      for (int c = 0; c < 4; ++c) {
        float l = (c == 0) ? a.x : (c == 1) ? a.y : (c == 2) ? a.z : a.w;
        zs += exp2f((l - M) * LOG2E_OVER_T);
        if (l > lo) {
          unsigned int p = atomicAdd(&s_nf, 1u);
          if (p < CAPSEG) { cvout[p] = l; ciout[p] = start + (i << 2) + c; }
        }
      }
    }
  }
  for (int i = (len4 << 2) + tid; i < len; i += BLK) {
    float l = base[i];
    zs += exp2f((l - M) * LOG2E_OVER_T);
    if (l > lo) {
      unsigned int p = atomicAdd(&s_nf, 1u);
      if (p < CAPSEG) { cvout[p] = l; ciout[p] = start + i; }
    }
  }
  #pragma unroll
  for (int off = 32; off >= 1; off >>= 1) zs += __shfl_xor(zs, off, 64);
  if (lane == 0) red[wave] = zs;
  __syncthreads();                                  // b2: done

  if (tid == 0) {
    float v = red[0];
    for (int w = 1; w < BLK / 64; ++w) v += red[w];
    segz[row * NSPLIT + seg] = v;                   // global-M anchor: plain sum
    unsigned int nf = s_nf;
    cnt16[row * NSPLIT + seg] = (nf > CAPSEG) ? (unsigned)CAPSEG : nf;
  }
}

__global__ __launch_bounds__(BLK_F)
void finish_kernel(const float* __restrict__ segmax, const float* __restrict__ segz,
                   const float* __restrict__ cand_v, const int* __restrict__ cand_i,
                   const unsigned int* __restrict__ cnt16,
                   const float* __restrict__ uvec, int* __restrict__ out)
{
  const int row  = blockIdx.x;
  const int tid  = threadIdx.x;
  const int lane = tid & 63;
  const int wave = tid >> 6;

  __shared__ unsigned int hist[NBINS];
  __shared__ unsigned int chunk[64];
  __shared__ unsigned int cnt_s[NSPLIT];
  __shared__ unsigned int pfx[NSPLIT];   // exclusive prefix of cnt_s
  __shared__ float s_M, s_Z;
  __shared__ int   s_n;
  __shared__ int   s_bstar;
  __shared__ unsigned int s_nc;
  __shared__ float dn_v[NDENSE];
  __shared__ int   dn_i[NDENSE];
  __shared__ float fv[CAPC];
  __shared__ int   fi[CAPC];
  __shared__ float ov_[CAPC];     // rank-ordered values
  __shared__ int   oi_[CAPC];     // rank-ordered indices
  __shared__ float eo[64];        // e per rank
  __shared__ float o2e[64];       // index-sorted kept e
  __shared__ int   o2i[64];
  __shared__ int   s_nk;

  if (tid < NSPLIT) cnt_s[tid] = cnt16[row * NSPLIT + tid];
  for (int i = tid; i < NBINS; i += BLK_F) hist[i] = 0u;
  __syncthreads();

  if (tid < 64) {
    float sm = segmax[row * NSEGA + lane];          // 64 A-segment maxes
    #pragma unroll
    for (int off = 32; off >= 1; off >>= 1) sm = fmaxf(sm, __shfl_xor(sm, off, 64));
    float zt = (lane < NSPLIT) ? segz[row * NSPLIT + lane] : 0.f;
    #pragma unroll
    for (int off = 32; off >= 1; off >>= 1) zt += __shfl_xor(zt, off, 64);
    // exclusive prefix over 32 counts: independent LDS broadcast reads
    if (lane < NSPLIT) {
      unsigned int p = 0;
      for (int j = 0; j < NSPLIT; ++j) {
        unsigned int cj = cnt_s[j];
        p += (j < lane) ? cj : 0u;
      }
      pfx[lane] = p;
    }
    if (lane == 0) { s_M = sm; s_Z = zt; s_nc = 0u; }
  }
  __syncthreads();
  if (tid == 0) {
    int t = (int)(pfx[NSPLIT - 1] + cnt_s[NSPLIT - 1]);
    s_n = (t > NDENSE) ? NDENSE : t;
  }
  __syncthreads();

  const float M  = s_M;
  const float lo = M - SPANC;
  const float binscale = (float)NBINS / SPANC;
  const int   n  = s_n;
  const float* cvrow = cand_v + (size_t)row * NCAND;
  const int*   cirow = cand_i + (size_t)row * NCAND;

  // dense gather: wave w handles segments w, w+4, ... (counts ~23 < 64)
  for (int sg = wave; sg < NSPLIT; sg += BLK_F / 64) {
    const unsigned int c  = cnt_s[sg];
    const unsigned int pb = pfx[sg];
    for (unsigned int i = lane; i < c; i += 64) {
      unsigned int d = pb + i;
      if (d < (unsigned)NDENSE) {
        dn_v[d] = cvrow[sg * CAPSEG + i];
        dn_i[d] = cirow[sg * CAPSEG + i];
      }
    }
  }
  __syncthreads();

  // histogram over dense candidates (all > lo by construction; clamp anyway)
  for (int i = tid; i < n; i += BLK_F) {
    float v = dn_v[i];
    int b = (int)((v - lo) * binscale);
    b = (b < 0) ? 0 : ((b > NBINS - 1) ? (NBINS - 1) : b);
    atomicAdd(&hist[b], 1u);
  }
  __syncthreads();

  if (tid < 64) {
    unsigned int csum = 0;
    const int cb = tid * BPL;
    #pragma unroll
    for (int j = 0; j < BPL; ++j) csum += hist[cb + j];
    chunk[tid] = csum;
  }
  __syncthreads();
  if (tid < 64) {
    unsigned int csum = chunk[tid];
    unsigned int suf = 0;
    for (int l2 = 0; l2 < 64; ++l2) {
      unsigned int c2 = chunk[l2];
      suf += (l2 >= tid) ? c2 : 0u;
    }
    unsigned long long bal = __ballot(suf >= (unsigned)TOPK);
    if (bal == 0ull) {
      if (tid == 0) s_bstar = 0;
    } else {
      int L = 63 - __builtin_clzll(bal);
      if (tid == L) {
        unsigned int running = suf - csum;
        const int cb = tid * BPL;
        unsigned int h[BPL];
        #pragma unroll
        for (int j = 0; j < BPL; ++j) h[j] = hist[cb + j];
        int bsel = cb;
        #pragma unroll
        for (int j = BPL - 1; j >= 0; --j) {
          running += h[j];
          if (running >= (unsigned)TOPK) { bsel = cb + j; break; }
        }
        s_bstar = bsel;
      }
    }
  }
  __syncthreads();

  // compact survivors (bin >= bstar) from dense array
  const int bstar = s_bstar;
  for (int i = tid; i < n; i += BLK_F) {
    float v = dn_v[i];
    int b = (int)((v - lo) * binscale);
    b = (b < 0) ? 0 : ((b > NBINS - 1) ? (NBINS - 1) : b);
    if (b >= bstar) {
      unsigned int p = atomicAdd(&s_nc, 1u);
      if (p < CAPC) { fv[p] = v; fi[p] = dn_i[i]; }
    }
  }
  __syncthreads();

  // all-pairs descending rank (value desc, index asc) + scatter
  const int ns = ((int)s_nc < CAPC) ? (int)s_nc : CAPC;
  if (tid < 64) {
    float c0v = (lane < ns)      ? fv[lane]      : 0.f;
    int   c0i = (lane < ns)      ? fi[lane]      : 0;
    float c1v = (lane + 64 < ns) ? fv[lane + 64] : 0.f;
    int   c1i = (lane + 64 < ns) ? fi[lane + 64] : 0;
    int r0 = 0, r1 = 0;
    for (int j = 0; j < ns; ++j) {
      float vj = fv[j]; int ij = fi[j];
      if (vj > c0v || (vj == c0v && ij < c0i)) ++r0;
      if (vj > c1v || (vj == c1v && ij < c1i)) ++r1;
    }
    if (lane < ns)      { ov_[r0] = c0v; oi_[r0] = c0i; }
    if (lane + 64 < ns) { ov_[r1] = c1v; oi_[r1] = c1i; }
  }
  __syncthreads();

  // per-rank exp on the exact reference path
  const float Mx = M / TEMP;                 // fl(M/0.7)
  if (tid < 64 && lane < ns && lane < TOPK) {
    float x = ov_[lane] / TEMP;              // fl(v/0.7) per element
    eo[lane] = expf(x - Mx);
  }
  __syncthreads();

  // sequential fp32 nucleus scan (lane 0)
  if (tid == 0) {
    const float thresh = 0.9f * s_Z;
    const int nkmax = (ns < TOPK) ? ns : TOPK;
    float cum = 0.f; int nk = 0;
    for (int k = 0; k < TOPK; ++k) {
      float ek = eo[k];
      bool take = (k < nkmax) && (cum < thresh);
      if (take) { cum += ek; nk++; }
    }
    s_nk = nk;
  }
  __syncthreads();

  // rank kept tokens by original index
  const int nk = s_nk;
  if (tid < 64 && lane < nk) {
    int myi = oi_[lane];
    int rank = 0;
    for (int j = 0; j < nk; ++j) rank += (oi_[j] < myi) ? 1 : 0;
    o2e[rank] = eo[lane]; o2i[rank] = myi;
  }
  __syncthreads();

  // sequential CDF sample (lane 0)
  if (tid == 0) {
    float S = 0.f;
    for (int j = 0; j < nk; ++j) S += o2e[j];
    const float uu = uvec[row];
    float c = 0.f; int token = 0; int found = 0;
    for (int j = 0; j < nk; ++j) {
      float q = o2e[j] / S;                  // mirrors softmax per-element divide
      c += q;
      if (!found && c >= uu) { token = o2i[j]; found = 1; }
    }
    out[row] = token;
  }
}

extern "C" void kernel_launch(void* const* d_in, const int* in_sizes, int n_in,
                              void* d_out, int out_size, void* d_ws, size_t ws_size,
                              hipStream_t stream) {
  const float* logits = (const float*)d_in[0];
  // d_in[1] = input_ids (unused: repetition_penalty == 1.0)
  const float* u = (const float*)d_in[2];
  int* out = (int*)d_out;
  const int B = in_sizes[2];
  const int V = in_sizes[0] / B;
  int seglenA = (V + NSEGA - 1) / NSEGA;   seglenA = (seglenA + 3) & ~3;
  int seglenB = (V + NSPLIT - 1) / NSPLIT; seglenB = (seglenB + 3) & ~3;

  // workspace layout (4-byte aligned):
  char* ws = (char*)d_ws;
  float* segmax = (float*)ws;                                   // B*NSEGA
  float* segz   = segmax + (size_t)B * NSEGA;                   // B*NSPLIT
  unsigned int* cnt16 = (unsigned int*)(segz + (size_t)B * NSPLIT); // B*NSPLIT
  float* cand_v = (float*)(cnt16 + (size_t)B * NSPLIT);         // B*NCAND
  int*   cand_i = (int*)(cand_v + (size_t)B * NCAND);           // B*NCAND

  max_kernel<<<dim3(NSEGA, B), dim3(BLK), 0, stream>>>(logits, segmax, V, seglenA);
  zcol_kernel<<<dim3(NSPLIT, B), dim3(BLK), 0, stream>>>(
      logits, segmax, segz, cand_v, cand_i, cnt16, V, seglenB);
  finish_kernel<<<dim3(B), dim3(BLK_F), 0, stream>>>(
      segmax, segz, cand_v, cand_i, cnt16, u, out);
}